// Round 2
// baseline (3453.649 us; speedup 1.0000x reference)
//
#include <hip/hip_runtime.h>
#include <math.h>

// Problem constants
constexpr int CVOC = 100;
constexpr int NCLS = 18;
constexpr int EE   = 512;   // word emb
constexpr int HHm  = 512;   // main GRU hidden
constexpr int CEc  = 128;   // char emb
constexpr int CHc  = 256;   // char GRU hidden
constexpr int BB   = 64;
constexpr int TT   = 64;
constexpr int CCh  = 16;    // chars per word
constexpr int NTOK = BB*TT;       // 4096
constexpr int G3C  = 3*CHc;       // 768
constexpr int G3H  = 3*HHm;       // 1536
constexpr int KIN  = EE + CHc;    // 768
constexpr int NBLK_GRU = 128;     // persistent main-GRU blocks (<=256 CUs -> co-resident)

__device__ __forceinline__ float sigmoidf_(float x){ return 1.0f/(1.0f + __expf(-x)); }
__device__ __forceinline__ float tanhf_(float x){ return 1.0f - 2.0f/(__expf(2.0f*x) + 1.0f); }

// ---------------------------------------------------------------------------
// K1: char input-projection table U2[c][g] = char_emb_W[c] . char_Wih[g] + bih[g]
//     (+ bhh[g] folded for r,z gates only)
__global__ void k_uchar(const float* __restrict__ cemb, const float* __restrict__ wih,
                        const float* __restrict__ bih, const float* __restrict__ bhh,
                        float* __restrict__ U2){
  const int c = blockIdx.x;        // 0..99
  const int g = threadIdx.x;       // 0..767
  const float* a = cemb + (size_t)c*CEc;
  const float* w = wih  + (size_t)g*CEc;
  float s = 0.f;
  for(int k=0;k<CEc;k++) s = fmaf(a[k], w[k], s);
  s += bih[g];
  if(g < 2*CHc) s += bhh[g];
  U2[(size_t)c*G3C + g] = s;
}

// ---------------------------------------------------------------------------
// generic transpose: in[R][C] -> out[C][R]
__global__ void k_transpose(const float* __restrict__ in, float* __restrict__ out,
                            int R, int C){
  int idx = blockIdx.x*blockDim.x + threadIdx.x;
  if(idx >= R*C) return;
  int k = idx / R;
  int j = idx % R;
  out[idx] = in[(size_t)j*C + k];
}

// ---------------------------------------------------------------------------
// K2: char GRU. 16 words per 256-thread block (256 blocks = 1/CU).
// thread = h-column. Weights streamed per-thread-contiguous (cWhh rows are
// k-contiguous already): 3x b128 global per 4-k chunk feeding 192 fma.
// h[w][k] reads are wave-uniform LDS broadcasts (conflict-free).
__global__ __launch_bounds__(256) void k_chargru(
    const int* __restrict__ chars, const float* __restrict__ U2,
    const float* __restrict__ Whh, const float* __restrict__ bhh,
    float* __restrict__ char_h){
  __shared__ float hsh[16][CHc];    // 16KB
  __shared__ int chsh[16];
  const int tid = threadIdx.x;
  const int w0 = blockIdx.x * 16;
  const float bhn = bhh[2*CHc + tid];
  const float* wrp = Whh + (size_t)tid*CHc;            // gate r row = tid
  const float* wzp = Whh + (size_t)(CHc + tid)*CHc;    // gate z
  const float* wnp = Whh + (size_t)(2*CHc + tid)*CHc;  // gate n
  #pragma unroll
  for(int w=0; w<16; w++) hsh[w][tid] = 0.f;
  for(int t=0; t<CCh; t++){
    __syncthreads();                       // hsh writes (t-1) + chsh reads (t-1) done
    if(tid < 16) chsh[tid] = chars[(size_t)(w0 + tid)*CCh + t];
    __syncthreads();
    float ar[16], az[16], an[16];
    #pragma unroll
    for(int w=0;w<16;w++){ ar[w]=0.f; az[w]=0.f; an[w]=0.f; }
    #pragma unroll 2
    for(int k=0; k<CHc; k+=4){
      float4 wr = *reinterpret_cast<const float4*>(wrp + k);
      float4 wz = *reinterpret_cast<const float4*>(wzp + k);
      float4 wn = *reinterpret_cast<const float4*>(wnp + k);
      #pragma unroll
      for(int w=0;w<16;w++){
        float4 hv = *reinterpret_cast<const float4*>(&hsh[w][k]);
        ar[w] = fmaf(hv.x,wr.x, fmaf(hv.y,wr.y, fmaf(hv.z,wr.z, fmaf(hv.w,wr.w, ar[w]))));
        az[w] = fmaf(hv.x,wz.x, fmaf(hv.y,wz.y, fmaf(hv.z,wz.z, fmaf(hv.w,wz.w, az[w]))));
        an[w] = fmaf(hv.x,wn.x, fmaf(hv.y,wn.y, fmaf(hv.z,wn.z, fmaf(hv.w,wn.w, an[w]))));
      }
    }
    __syncthreads();                       // dot-loop hsh reads done before overwrite
    #pragma unroll
    for(int w=0;w<16;w++){
      const float* u = U2 + (size_t)chsh[w]*G3C;
      float r = sigmoidf_(u[tid]        + ar[w]);
      float z = sigmoidf_(u[CHc+tid]    + az[w]);
      float n = tanhf_   (u[2*CHc+tid]  + r*(an[w] + bhn));
      float hp = hsh[w][tid];
      hsh[w][tid] = (1.f - z)*n + z*hp;
    }
  }
  __syncthreads();
  #pragma unroll
  for(int w=0;w<16;w++) char_h[(size_t)(w0+w)*CHc + tid] = hsh[w][tid];
}

// ---------------------------------------------------------------------------
// K3: gx projection GEMM, M=4096(tokens) N=1536 K=768, 128x96 tiles, 8x6 micro,
// 512 blocks (2/CU balanced). Output written TRANSPOSED: gxT[t][g][b] so the
// recurrence reads are lane-coalesced. bias folded (+bhh for r,z gates).
__global__ __launch_bounds__(256) void k_gxmain(
    const int* __restrict__ x, const float* __restrict__ wemb,
    const float* __restrict__ chh, const float* __restrict__ WihT,
    const float* __restrict__ bih, const float* __restrict__ bhh,
    float* __restrict__ gxT){
  __shared__ float As[128][20];   // [m][k] pad 20 (b128-aligned, low-conflict)
  __shared__ float Bs[16][100];   // [k][n] pad 100
  __shared__ int xs[128];
  const int tid = threadIdx.x;
  const int rb = blockIdx.x * 128;
  const int nb = blockIdx.y * 96;
  if(tid < 128) xs[tid] = x[rb + tid];
  const int tr = tid >> 4, tc = tid & 15;
  float acc[8][6];
  #pragma unroll
  for(int i=0;i<8;i++)
    #pragma unroll
    for(int j=0;j<6;j++) acc[i][j]=0.f;
  __syncthreads();
  for(int kb=0; kb<KIN; kb+=16){
    #pragma unroll
    for(int i=0;i<2;i++){
      int idx = i*256 + tid;
      int m = idx & 127, kq = idx >> 7;
      int k = kb + kq*4;
      float4 v;
      if(k < EE) v = *reinterpret_cast<const float4*>(&wemb[(size_t)xs[m]*EE + k]);
      else       v = *reinterpret_cast<const float4*>(&chh[(size_t)(rb+m)*CHc + (k-EE)]);
      *reinterpret_cast<float4*>(&As[m][kq*4]) = v;
    }
    #pragma unroll
    for(int i=0;i<2;i++){
      int idx = i*256 + tid;
      if(idx < 384){
        int k = idx / 24, n4 = (idx % 24)*4;
        *reinterpret_cast<float4*>(&Bs[k][n4]) =
            *reinterpret_cast<const float4*>(&WihT[(size_t)(kb+k)*G3H + nb + n4]);
      }
    }
    __syncthreads();
    #pragma unroll
    for(int k=0;k<16;k++){
      float a[8];
      #pragma unroll
      for(int i=0;i<4;i++){ a[i]=As[tr*4+i][k]; a[4+i]=As[64+tr*4+i][k]; }
      float2 b0 = *reinterpret_cast<const float2*>(&Bs[k][tc*2]);
      float2 b1 = *reinterpret_cast<const float2*>(&Bs[k][32+tc*2]);
      float2 b2 = *reinterpret_cast<const float2*>(&Bs[k][64+tc*2]);
      float b[6] = {b0.x,b0.y,b1.x,b1.y,b2.x,b2.y};
      #pragma unroll
      for(int i=0;i<8;i++)
        #pragma unroll
        for(int j=0;j<6;j++)
          acc[i][j] = fmaf(a[i], b[j], acc[i][j]);
    }
    __syncthreads();
  }
  #pragma unroll
  for(int i=0;i<8;i++){
    int row = rb + ((i<4) ? tr*4+i : 64 + tr*4 + (i-4));
    int b = row >> 6, t = row & 63;           // token = b*T + t
    #pragma unroll
    for(int j=0;j<6;j++){
      int g = nb + (j>>1)*32 + tc*2 + (j&1);
      float v = acc[i][j] + bih[g] + (g < 2*HHm ? bhh[g] : 0.f);
      gxT[((size_t)t*G3H + g)*64 + b] = v;
    }
  }
}

// ---------------------------------------------------------------------------
// K4: persistent main GRU. 128 blocks x 256 threads, thread=(r=lane, c=wave),
// block owns 4 h-cols. Weights read direct from gWhh (L1-resident 24KB/block,
// wave-uniform addresses). h staged in LDS per step; grid-wide spin barrier
// (per-step arrival counters, device-scope acq/rel) between steps.
__global__ __launch_bounds__(256) void k_grumain(
    float* __restrict__ hA, float* __restrict__ hB,
    const float* __restrict__ Whh, const float* __restrict__ gxT,
    const float* __restrict__ bhh, float* __restrict__ outhT,
    int* __restrict__ bar){
  __shared__ float hch[128][68];   // 34.8KB h chunk [k][r]
  const int tid = threadIdx.x;
  const int r = tid & 63;
  const int c = tid >> 6;                 // wave-uniform
  const int j = blockIdx.x*4 + c;
  const float bhn = bhh[2*HHm + j];
  const float* wr = Whh + (size_t)(0*HHm + j)*HHm;
  const float* wz = Whh + (size_t)(1*HHm + j)*HHm;
  const float* wn = Whh + (size_t)(2*HHm + j)*HHm;
  float* hin = hA;
  float* hout = hB;
  for(int t=0; t<TT; t++){
    // prefetch gx for this step (coalesced from gxT)
    float gxr = gxT[((size_t)t*G3H +           j)*64 + r];
    float gxz = gxT[((size_t)t*G3H + HHm +     j)*64 + r];
    float gxn = gxT[((size_t)t*G3H + 2*HHm +   j)*64 + r];
    float accr=0.f, accz=0.f, accn=0.f;
    float hold = 0.f;
    for(int kc=0; kc<4; kc++){
      __syncthreads();
      #pragma unroll
      for(int i=0;i<8;i++){
        int f4 = i*256 + tid;
        int kk = f4 >> 4, rr = (f4 & 15)*4;
        *reinterpret_cast<float4*>(&hch[kk][rr]) =
            *reinterpret_cast<const float4*>(&hin[((size_t)kc*128 + kk)*64 + rr]);
      }
      __syncthreads();
      if(kc == (j >> 7)) hold = hch[j & 127][r];   // wave-uniform branch
      #pragma unroll 2
      for(int kk=0; kk<128; kk+=4){
        int kg = kc*128 + kk;
        float4 wrv = *reinterpret_cast<const float4*>(wr + kg);
        float4 wzv = *reinterpret_cast<const float4*>(wz + kg);
        float4 wnv = *reinterpret_cast<const float4*>(wn + kg);
        float h0 = hch[kk+0][r], h1 = hch[kk+1][r], h2 = hch[kk+2][r], h3 = hch[kk+3][r];
        accr = fmaf(h0,wrv.x, fmaf(h1,wrv.y, fmaf(h2,wrv.z, fmaf(h3,wrv.w, accr))));
        accz = fmaf(h0,wzv.x, fmaf(h1,wzv.y, fmaf(h2,wzv.z, fmaf(h3,wzv.w, accz))));
        accn = fmaf(h0,wnv.x, fmaf(h1,wnv.y, fmaf(h2,wnv.z, fmaf(h3,wnv.w, accn))));
      }
    }
    float rg = sigmoidf_(gxr + accr);
    float zg = sigmoidf_(gxz + accz);
    float ng = tanhf_   (gxn + rg*(accn + bhn));
    float hnew = (1.f - zg)*ng + zg*hold;
    hout[(size_t)j*64 + r] = hnew;
    outhT[((size_t)t*HHm + j)*64 + r] = hnew;
    if(t < TT-1){
      __threadfence();                     // release my h writes (device scope)
      __syncthreads();
      if(tid == 0){
        __hip_atomic_fetch_add(&bar[t], 1, __ATOMIC_ACQ_REL, __HIP_MEMORY_SCOPE_AGENT);
        while(__hip_atomic_load(&bar[t], __ATOMIC_ACQUIRE, __HIP_MEMORY_SCOPE_AGENT) < NBLK_GRU){
          __builtin_amdgcn_s_sleep(1);
        }
      }
      __syncthreads();
      // per-wave acquire: invalidate stale L1 lines before reading others' h
      __hip_atomic_load(&bar[t], __ATOMIC_ACQUIRE, __HIP_MEMORY_SCOPE_AGENT);
    }
    float* tmp = hin; hin = hout; hout = tmp;
  }
}

// ---------------------------------------------------------------------------
// K5: classifier. One block per time-step t.
__global__ __launch_bounds__(256) void k_cls(
    const float* __restrict__ outhT, const float* __restrict__ clsW,
    const float* __restrict__ clsb, float* __restrict__ out){
  __shared__ float wls[20*HHm];     // 40KB (padded 18->20 rows)
  __shared__ float hch[64][68];     // 17.4KB
  const int tid = threadIdx.x;
  const int t = blockIdx.x;
  const int r = tid & 63;
  const int q = tid >> 6;
  const int c0 = q*5;
  for(int f = tid*4; f < 20*HHm; f += 1024){
    float4 v = make_float4(0.f,0.f,0.f,0.f);
    if(f < NCLS*HHm) v = *reinterpret_cast<const float4*>(&clsW[f]);
    *reinterpret_cast<float4*>(&wls[f]) = v;
  }
  float acc[5] = {0.f,0.f,0.f,0.f,0.f};
  for(int kc=0; kc<8; kc++){
    __syncthreads();
    #pragma unroll
    for(int i=0;i<4;i++){
      int f4 = i*256 + tid;
      int kk = f4 >> 4, rr = (f4 & 15)*4;
      *reinterpret_cast<float4*>(&hch[kk][rr]) =
          *reinterpret_cast<const float4*>(&outhT[((size_t)t*HHm + kc*64 + kk)*64 + rr]);
    }
    __syncthreads();
    for(int k=0;k<64;k++){
      float hv = hch[k][r];
      #pragma unroll
      for(int i=0;i<5;i++)
        acc[i] = fmaf(hv, wls[(size_t)(c0+i)*HHm + kc*64 + k], acc[i]);
    }
  }
  #pragma unroll
  for(int i=0;i<5;i++){
    int cls = c0 + i;
    if(cls < NCLS) out[((size_t)r*TT + t)*NCLS + cls] = acc[i] + clsb[cls];
  }
}

// ---------------------------------------------------------------------------
extern "C" void kernel_launch(void* const* d_in, const int* in_sizes, int n_in,
                              void* d_out, int out_size, void* d_ws, size_t ws_size,
                              hipStream_t stream){
  const int*   x     = (const int*)d_in[0];
  const int*   chars = (const int*)d_in[1];
  const float* wemb  = (const float*)d_in[2];
  const float* cemb  = (const float*)d_in[3];
  const float* cWih  = (const float*)d_in[4];
  const float* cWhh  = (const float*)d_in[5];
  const float* cbih  = (const float*)d_in[6];
  const float* cbhh  = (const float*)d_in[7];
  const float* gWih  = (const float*)d_in[8];
  const float* gWhh  = (const float*)d_in[9];
  const float* gbih  = (const float*)d_in[10];
  const float* gbhh  = (const float*)d_in[11];
  const float* clsW  = (const float*)d_in[12];
  const float* clsb  = (const float*)d_in[13];
  float* out = (float*)d_out;
  float* ws  = (float*)d_ws;

  // workspace layout (floats)
  float* U2    = ws;                   // 100*768    = 76800
  float* WihTm = U2 + 76800;           // 768*1536   = 1179648
  float* chh   = WihTm + 1179648;      // 4096*256   = 1048576
  float* gxT   = chh + 1048576;        // 64*1536*64 = 6291456  [t][g][b]
  float* hA    = gxT + 6291456;        // 512*64
  float* hB    = hA + 32768;           // 512*64
  float* ohT   = hB + 32768;           // 64*512*64  = 2097152  [t][j][r]
  int*   bar   = (int*)(ohT + 2097152);// 64 step counters

  hipMemsetAsync(hA, 0, 32768*sizeof(float), stream);   // h0 = 0
  hipMemsetAsync(bar, 0, 64*sizeof(int), stream);       // barrier counters
  k_uchar<<<CVOC, G3C, 0, stream>>>(cemb, cWih, cbih, cbhh, U2);
  k_transpose<<<(G3H*KIN + 255)/256, 256, 0, stream>>>(gWih, WihTm, G3H, KIN);
  k_chargru<<<NTOK/16, 256, 0, stream>>>(chars, U2, cWhh, cbhh, chh);
  k_gxmain<<<dim3(NTOK/128, G3H/96), 256, 0, stream>>>(x, wemb, chh, WihTm, gbih, gbhh, gxT);
  k_grumain<<<NBLK_GRU, 256, 0, stream>>>(hA, hB, gWhh, gxT, gbhh, ohT, bar);
  k_cls<<<TT, 256, 0, stream>>>(ohT, clsW, clsb, out);
}

// Round 4
// 2060.418 us; speedup vs baseline: 1.6762x; 1.6762x over previous
//
#include <hip/hip_runtime.h>
#include <math.h>

// Problem constants
constexpr int CVOC = 100;
constexpr int NCLS = 18;
constexpr int EE   = 512;   // word emb
constexpr int HHm  = 512;   // main GRU hidden
constexpr int CEc  = 128;   // char emb
constexpr int CHc  = 256;   // char GRU hidden
constexpr int BB   = 64;
constexpr int TT   = 64;
constexpr int CCh  = 16;    // chars per word
constexpr int NTOK = BB*TT;       // 4096
constexpr int G3C  = 3*CHc;       // 768
constexpr int G3H  = 3*HHm;       // 1536
constexpr int KIN  = EE + CHc;    // 768
constexpr int GRU_BLOCKS = 64;    // persistent main-GRU blocks (co-resident)

__device__ __forceinline__ float sigmoidf_(float x){ return 1.0f/(1.0f + __expf(-x)); }
__device__ __forceinline__ float tanhf_(float x){ return 1.0f - 2.0f/(__expf(2.0f*x) + 1.0f); }

// ---------------------------------------------------------------------------
// K1: char input-projection table U2[c][g] = char_emb_W[c] . char_Wih[g] + bih[g]
//     (+ bhh[g] folded for r,z gates only)
__global__ void k_uchar(const float* __restrict__ cemb, const float* __restrict__ wih,
                        const float* __restrict__ bih, const float* __restrict__ bhh,
                        float* __restrict__ U2){
  const int c = blockIdx.x;        // 0..99
  const int g = threadIdx.x;       // 0..767
  const float* a = cemb + (size_t)c*CEc;
  const float* w = wih  + (size_t)g*CEc;
  float s = 0.f;
  for(int k=0;k<CEc;k++) s = fmaf(a[k], w[k], s);
  s += bih[g];
  if(g < 2*CHc) s += bhh[g];
  U2[(size_t)c*G3C + g] = s;
}

// ---------------------------------------------------------------------------
// generic transpose: in[R][C] -> out[C][R]
__global__ void k_transpose(const float* __restrict__ in, float* __restrict__ out,
                            int R, int C){
  int idx = blockIdx.x*blockDim.x + threadIdx.x;
  if(idx >= R*C) return;
  int k = idx / R;
  int j = idx % R;
  out[idx] = in[(size_t)j*C + k];
}

// ---------------------------------------------------------------------------
// K2: char GRU. 16 words per 256-thread block. thread = h-column.
// Weights streamed per-thread-contiguous from cWhh rows; h in LDS (broadcasts).
__global__ __launch_bounds__(256) void k_chargru(
    const int* __restrict__ chars, const float* __restrict__ U2,
    const float* __restrict__ Whh, const float* __restrict__ bhh,
    float* __restrict__ char_h){
  __shared__ float hsh[16][CHc];    // 16KB
  __shared__ int chsh[16];
  const int tid = threadIdx.x;
  const int w0 = blockIdx.x * 16;
  const float bhn = bhh[2*CHc + tid];
  const float* wrp = Whh + (size_t)tid*CHc;            // gate r row = tid
  const float* wzp = Whh + (size_t)(CHc + tid)*CHc;    // gate z
  const float* wnp = Whh + (size_t)(2*CHc + tid)*CHc;  // gate n
  #pragma unroll
  for(int w=0; w<16; w++) hsh[w][tid] = 0.f;
  for(int t=0; t<CCh; t++){
    __syncthreads();
    if(tid < 16) chsh[tid] = chars[(size_t)(w0 + tid)*CCh + t];
    __syncthreads();
    float ar[16], az[16], an[16];
    #pragma unroll
    for(int w=0;w<16;w++){ ar[w]=0.f; az[w]=0.f; an[w]=0.f; }
    #pragma unroll 2
    for(int k=0; k<CHc; k+=4){
      float4 wr = *reinterpret_cast<const float4*>(wrp + k);
      float4 wz = *reinterpret_cast<const float4*>(wzp + k);
      float4 wn = *reinterpret_cast<const float4*>(wnp + k);
      #pragma unroll
      for(int w=0;w<16;w++){
        float4 hv = *reinterpret_cast<const float4*>(&hsh[w][k]);
        ar[w] = fmaf(hv.x,wr.x, fmaf(hv.y,wr.y, fmaf(hv.z,wr.z, fmaf(hv.w,wr.w, ar[w]))));
        az[w] = fmaf(hv.x,wz.x, fmaf(hv.y,wz.y, fmaf(hv.z,wz.z, fmaf(hv.w,wz.w, az[w]))));
        an[w] = fmaf(hv.x,wn.x, fmaf(hv.y,wn.y, fmaf(hv.z,wn.z, fmaf(hv.w,wn.w, an[w]))));
      }
    }
    __syncthreads();
    #pragma unroll
    for(int w=0;w<16;w++){
      const float* u = U2 + (size_t)chsh[w]*G3C;
      float r = sigmoidf_(u[tid]        + ar[w]);
      float z = sigmoidf_(u[CHc+tid]    + az[w]);
      float n = tanhf_   (u[2*CHc+tid]  + r*(an[w] + bhn));
      float hp = hsh[w][tid];
      hsh[w][tid] = (1.f - z)*n + z*hp;
    }
  }
  __syncthreads();
  #pragma unroll
  for(int w=0;w<16;w++) char_h[(size_t)(w0+w)*CHc + tid] = hsh[w][tid];
}

// ---------------------------------------------------------------------------
// K3: gx GEMM, M=4096 tokens, N=1536, K=768; 128x96 tiles; ROW-MAJOR output
// gx[token][g] with bias folded (+bhh for r,z gates).
__global__ __launch_bounds__(256) void k_gxmain(
    const int* __restrict__ x, const float* __restrict__ wemb,
    const float* __restrict__ chh, const float* __restrict__ WihT,
    const float* __restrict__ bih, const float* __restrict__ bhh,
    float* __restrict__ gx){
  __shared__ float As[128][20];
  __shared__ float Bs[16][100];
  __shared__ int xs[128];
  const int tid = threadIdx.x;
  const int rb = blockIdx.x * 128;
  const int nb = blockIdx.y * 96;
  if(tid < 128) xs[tid] = x[rb + tid];
  const int tr = tid >> 4, tc = tid & 15;
  float acc[8][6];
  #pragma unroll
  for(int i=0;i<8;i++)
    #pragma unroll
    for(int j=0;j<6;j++) acc[i][j]=0.f;
  __syncthreads();
  for(int kb=0; kb<KIN; kb+=16){
    #pragma unroll
    for(int i=0;i<2;i++){
      int idx = i*256 + tid;
      int m = idx & 127, kq = idx >> 7;
      int k = kb + kq*4;
      float4 v;
      if(k < EE) v = *reinterpret_cast<const float4*>(&wemb[(size_t)xs[m]*EE + k]);
      else       v = *reinterpret_cast<const float4*>(&chh[(size_t)(rb+m)*CHc + (k-EE)]);
      *reinterpret_cast<float4*>(&As[m][kq*4]) = v;
    }
    #pragma unroll
    for(int i=0;i<2;i++){
      int idx = i*256 + tid;
      if(idx < 384){
        int k = idx / 24, n4 = (idx % 24)*4;
        *reinterpret_cast<float4*>(&Bs[k][n4]) =
            *reinterpret_cast<const float4*>(&WihT[(size_t)(kb+k)*G3H + nb + n4]);
      }
    }
    __syncthreads();
    #pragma unroll
    for(int k=0;k<16;k++){
      float a[8];
      #pragma unroll
      for(int i=0;i<4;i++){ a[i]=As[tr*4+i][k]; a[4+i]=As[64+tr*4+i][k]; }
      float2 b0 = *reinterpret_cast<const float2*>(&Bs[k][tc*2]);
      float2 b1 = *reinterpret_cast<const float2*>(&Bs[k][32+tc*2]);
      float2 b2 = *reinterpret_cast<const float2*>(&Bs[k][64+tc*2]);
      float b[6] = {b0.x,b0.y,b1.x,b1.y,b2.x,b2.y};
      #pragma unroll
      for(int i=0;i<8;i++)
        #pragma unroll
        for(int j=0;j<6;j++)
          acc[i][j] = fmaf(a[i], b[j], acc[i][j]);
    }
    __syncthreads();
  }
  #pragma unroll
  for(int i=0;i<8;i++){
    int row = rb + ((i<4) ? tr*4+i : 64 + tr*4 + (i-4));
    #pragma unroll
    for(int j=0;j<6;j++){
      int g = nb + (j>>1)*32 + tc*2 + (j&1);
      float v = acc[i][j] + bih[g] + (g < 2*HHm ? bhh[g] : 0.f);
      gx[(size_t)row*G3H + g] = v;
    }
  }
}

// ---------------------------------------------------------------------------
// K4: persistent main GRU, fence-free coherent h exchange.
// 64 blocks = (jb 16 x bb 4). 512 threads = 8 waves (kw = k-slice of 64);
// lane = (j' 32, bh 2). Weights per-lane from global (L1/L2-hot); h staged in
// LDS. h ping-pong via RELAXED AGENT atomics (per-access coherent, no fences).
// Writer-side ordering hardened: h "store" is an atomic_exchange whose return
// value is consumed (asm operand) -> vmcnt wait until the RMW completed at the
// coherence point, BEFORE __syncthreads -> bar increment. Reader side: relaxed
// agent atomic loads bypass stale caches by construction.
__global__ __launch_bounds__(512) void k_grumain(
    float* __restrict__ hA, float* __restrict__ hB,
    const float* __restrict__ Whh, const float* __restrict__ gx,
    const float* __restrict__ bhh, float* __restrict__ outh,
    int* __restrict__ bar){
  __shared__ float hsh[16][516];     // 33KB   h_{t-1}[b][k], padded
  __shared__ float red[48][32][8];   // 49KB   partials [g*16+b][j'][kw]
  const int tid  = threadIdx.x;
  const int lane = tid & 63;
  const int kw   = tid >> 6;         // 0..7
  const int jp   = lane & 31;
  const int bh   = lane >> 5;        // 0/1
  const int jb   = blockIdx.x & 15;
  const int bb   = blockIdx.x >> 4;  // 0..3
  const int jglob = jb*32 + jp;
  const float* wR = Whh + (size_t)(0*HHm + jglob)*HHm;
  const float* wZ = Whh + (size_t)(1*HHm + jglob)*HHm;
  const float* wN = Whh + (size_t)(2*HHm + jglob)*HHm;
  const int k0 = kw*64;
  float* hin = hA; float* hout = hB;
  for(int t=0; t<TT; t++){
    // stage h_{t-1} slice [bb*16..+16)[0..512) -- coherent (agent) loads
    for(int i=0;i<16;i++){
      int f = i*512 + tid;
      int b = f >> 9, k = f & 511;
      hsh[b][k] = __hip_atomic_load(&hin[(size_t)(bb*16+b)*HHm + k],
                                    __ATOMIC_RELAXED, __HIP_MEMORY_SCOPE_AGENT);
    }
    __syncthreads();
    float accR[8], accZ[8], accN[8];
    #pragma unroll
    for(int i=0;i<8;i++){ accR[i]=0.f; accZ[i]=0.f; accN[i]=0.f; }
    for(int kk=k0; kk<k0+64; kk+=4){
      float4 r4 = *reinterpret_cast<const float4*>(wR + kk);
      float4 z4 = *reinterpret_cast<const float4*>(wZ + kk);
      float4 n4 = *reinterpret_cast<const float4*>(wN + kk);
      #pragma unroll
      for(int bi=0; bi<8; bi++){
        float4 h4 = *reinterpret_cast<const float4*>(&hsh[bh*8 + bi][kk]);
        accR[bi] = fmaf(h4.x,r4.x, fmaf(h4.y,r4.y, fmaf(h4.z,r4.z, fmaf(h4.w,r4.w, accR[bi]))));
        accZ[bi] = fmaf(h4.x,z4.x, fmaf(h4.y,z4.y, fmaf(h4.z,z4.z, fmaf(h4.w,z4.w, accZ[bi]))));
        accN[bi] = fmaf(h4.x,n4.x, fmaf(h4.y,n4.y, fmaf(h4.z,n4.z, fmaf(h4.w,n4.w, accN[bi]))));
      }
    }
    #pragma unroll
    for(int bi=0;bi<8;bi++){
      int b = bh*8 + bi;
      red[0*16 + b][jp][kw] = accR[bi];
      red[1*16 + b][jp][kw] = accZ[bi];
      red[2*16 + b][jp][kw] = accN[bi];
    }
    __syncthreads();
    {
      // finalize: tid -> (b = tid>>5, j2 = tid&31)
      const int b  = tid >> 5;          // 0..15
      const int j2 = tid & 31;
      const int jg = jb*32 + j2;
      float sR=0.f, sZ=0.f, sN=0.f;
      #pragma unroll
      for(int w=0; w<8; w++){
        sR += red[0*16+b][j2][w];
        sZ += red[1*16+b][j2][w];
        sN += red[2*16+b][j2][w];
      }
      const int bglob = bb*16 + b;
      const size_t tok = (size_t)bglob*TT + t;
      float gxr = gx[tok*G3H + jg];
      float gxz = gx[tok*G3H + HHm + jg];
      float gxn = gx[tok*G3H + 2*HHm + jg];
      float rg = sigmoidf_(gxr + sR);
      float zg = sigmoidf_(gxz + sZ);
      float ng = tanhf_   (gxn + rg*(sN + bhh[2*HHm + jg]));
      float hnew = (1.f - zg)*ng + zg*hsh[b][jg];
      // coherent-point RMW; consuming 'old' forces wait-for-completion
      float old = __hip_atomic_exchange(&hout[(size_t)bglob*HHm + jg], hnew,
                                        __ATOMIC_RELAXED, __HIP_MEMORY_SCOPE_AGENT);
      asm volatile("" :: "v"(old));
      outh[((size_t)t*BB + bglob)*HHm + jg] = hnew;   // [t][b][j]
    }
    if(t < TT-1){
      __syncthreads();   // exec barrier: all 512 threads' exchanges completed
      if(tid == 0){
        __hip_atomic_fetch_add(&bar[t], 1, __ATOMIC_RELAXED, __HIP_MEMORY_SCOPE_AGENT);
        while(__hip_atomic_load(&bar[t], __ATOMIC_RELAXED, __HIP_MEMORY_SCOPE_AGENT) < GRU_BLOCKS)
          __builtin_amdgcn_s_sleep(2);
      }
      __syncthreads();
    }
    float* tmp = hin; hin = hout; hout = tmp;
  }
}

// ---------------------------------------------------------------------------
// K5: classifier. One block per time-step t; reads outh[t][b][j].
__global__ __launch_bounds__(256) void k_cls(
    const float* __restrict__ outh, const float* __restrict__ clsW,
    const float* __restrict__ clsb, float* __restrict__ out){
  __shared__ float wls[20*HHm];     // 40KB (padded 18->20 rows)
  __shared__ float hch[64][129];    // 33KB  [b][k], stride 129 -> conflict-free
  const int tid = threadIdx.x;
  const int t = blockIdx.x;
  const int b = tid & 63;
  const int q = tid >> 6;
  const int c0 = q*5;
  for(int f = tid*4; f < 20*HHm; f += 1024){
    float4 v = make_float4(0.f,0.f,0.f,0.f);
    if(f < NCLS*HHm) v = *reinterpret_cast<const float4*>(&clsW[f]);
    *reinterpret_cast<float4*>(&wls[f]) = v;
  }
  float acc[5] = {0.f,0.f,0.f,0.f,0.f};
  for(int kc=0; kc<4; kc++){
    __syncthreads();
    for(int i=0;i<32;i++){
      int f = i*256 + tid;            // 0..8191: full coverage
      int b2 = f >> 7, kk = f & 127;
      hch[b2][kk] = outh[((size_t)t*BB + b2)*HHm + kc*128 + kk];
    }
    __syncthreads();
    for(int k=0;k<128;k++){
      float hv = hch[b][k];
      #pragma unroll
      for(int i=0;i<5;i++)
        acc[i] = fmaf(hv, wls[(size_t)(c0+i)*HHm + kc*128 + k], acc[i]);
    }
  }
  #pragma unroll
  for(int i=0;i<5;i++){
    int cls = c0 + i;
    if(cls < NCLS) out[((size_t)b*TT + t)*NCLS + cls] = acc[i] + clsb[cls];
  }
}

// ---------------------------------------------------------------------------
extern "C" void kernel_launch(void* const* d_in, const int* in_sizes, int n_in,
                              void* d_out, int out_size, void* d_ws, size_t ws_size,
                              hipStream_t stream){
  const int*   x     = (const int*)d_in[0];
  const int*   chars = (const int*)d_in[1];
  const float* wemb  = (const float*)d_in[2];
  const float* cemb  = (const float*)d_in[3];
  const float* cWih  = (const float*)d_in[4];
  const float* cWhh  = (const float*)d_in[5];
  const float* cbih  = (const float*)d_in[6];
  const float* cbhh  = (const float*)d_in[7];
  const float* gWih  = (const float*)d_in[8];
  const float* gWhh  = (const float*)d_in[9];
  const float* gbih  = (const float*)d_in[10];
  const float* gbhh  = (const float*)d_in[11];
  const float* clsW  = (const float*)d_in[12];
  const float* clsb  = (const float*)d_in[13];
  float* out = (float*)d_out;
  float* ws  = (float*)d_ws;

  // workspace layout (floats)
  float* U2    = ws;                   // 100*768    = 76800
  float* WihTm = U2 + 76800;           // 768*1536   = 1179648
  float* chh   = WihTm + 1179648;      // 4096*256   = 1048576
  float* gx    = chh + 1048576;        // 4096*1536  = 6291456   [token][g]
  float* hA    = gx + 6291456;         // 64*512
  float* hB    = hA + 32768;           // 64*512
  float* outh  = hB + 32768;           // 64*64*512  = 2097152   [t][b][j]
  int*   bar   = (int*)(outh + 2097152);

  hipMemsetAsync(hA, 0, 32768*sizeof(float), stream);   // h0 = 0
  hipMemsetAsync(bar, 0, 64*sizeof(int), stream);       // per-step arrival counters
  k_uchar<<<CVOC, G3C, 0, stream>>>(cemb, cWih, cbih, cbhh, U2);
  k_transpose<<<(G3H*KIN + 255)/256, 256, 0, stream>>>(gWih, WihTm, G3H, KIN);
  k_chargru<<<NTOK/16, 256, 0, stream>>>(chars, U2, cWhh, cbhh, chh);
  k_gxmain<<<dim3(NTOK/128, G3H/96), 256, 0, stream>>>(x, wemb, chh, WihTm, gbih, gbhh, gx);
  k_grumain<<<GRU_BLOCKS, 512, 0, stream>>>(hA, hB, gWhh, gx, gbhh, outh, bar);
  k_cls<<<TT, 256, 0, stream>>>(outh, clsW, clsb, out);
}

// Round 5
// 1800.250 us; speedup vs baseline: 1.9184x; 1.1445x over previous
//
#include <hip/hip_runtime.h>
#include <math.h>

// Problem constants
constexpr int CVOC = 100;
constexpr int NCLS = 18;
constexpr int EE   = 512;   // word emb
constexpr int HHm  = 512;   // main GRU hidden
constexpr int CEc  = 128;   // char emb
constexpr int CHc  = 256;   // char GRU hidden
constexpr int BB   = 64;
constexpr int TT   = 64;
constexpr int CCh  = 16;    // chars per word
constexpr int NTOK = BB*TT;       // 4096
constexpr int G3C  = 3*CHc;       // 768
constexpr int G3H  = 3*HHm;       // 1536
constexpr int KIN  = EE + CHc;    // 768

__device__ __forceinline__ float sigmoidf_(float x){ return 1.0f/(1.0f + __expf(-x)); }
__device__ __forceinline__ float tanhf_(float x){ return 1.0f - 2.0f/(__expf(2.0f*x) + 1.0f); }

// ---------------------------------------------------------------------------
// K1: char input-projection table U2[c][g] = char_emb_W[c] . char_Wih[g] + bih[g]
//     (+ bhh[g] folded for r,z gates only)
__global__ void k_uchar(const float* __restrict__ cemb, const float* __restrict__ wih,
                        const float* __restrict__ bih, const float* __restrict__ bhh,
                        float* __restrict__ U2){
  const int c = blockIdx.x;        // 0..99
  const int g = threadIdx.x;       // 0..767
  const float* a = cemb + (size_t)c*CEc;
  const float* w = wih  + (size_t)g*CEc;
  float s = 0.f;
  for(int k=0;k<CEc;k++) s = fmaf(a[k], w[k], s);
  s += bih[g];
  if(g < 2*CHc) s += bhh[g];
  U2[(size_t)c*G3C + g] = s;
}

// ---------------------------------------------------------------------------
// generic transpose: in[R][C] -> out[C][R]
__global__ void k_transpose(const float* __restrict__ in, float* __restrict__ out,
                            int R, int C){
  int idx = blockIdx.x*blockDim.x + threadIdx.x;
  if(idx >= R*C) return;
  int k = idx / R;
  int j = idx % R;
  out[idx] = in[(size_t)j*C + k];
}

// ---------------------------------------------------------------------------
// K2: char GRU. 16 words per 256-thread block. thread = h-column.
__global__ __launch_bounds__(256) void k_chargru(
    const int* __restrict__ chars, const float* __restrict__ U2,
    const float* __restrict__ Whh, const float* __restrict__ bhh,
    float* __restrict__ char_h){
  __shared__ float hsh[16][CHc];    // 16KB
  __shared__ int chsh[16];
  const int tid = threadIdx.x;
  const int w0 = blockIdx.x * 16;
  const float bhn = bhh[2*CHc + tid];
  const float* wrp = Whh + (size_t)tid*CHc;            // gate r row = tid
  const float* wzp = Whh + (size_t)(CHc + tid)*CHc;    // gate z
  const float* wnp = Whh + (size_t)(2*CHc + tid)*CHc;  // gate n
  #pragma unroll
  for(int w=0; w<16; w++) hsh[w][tid] = 0.f;
  for(int t=0; t<CCh; t++){
    __syncthreads();
    if(tid < 16) chsh[tid] = chars[(size_t)(w0 + tid)*CCh + t];
    __syncthreads();
    float ar[16], az[16], an[16];
    #pragma unroll
    for(int w=0;w<16;w++){ ar[w]=0.f; az[w]=0.f; an[w]=0.f; }
    #pragma unroll 2
    for(int k=0; k<CHc; k+=4){
      float4 wr = *reinterpret_cast<const float4*>(wrp + k);
      float4 wz = *reinterpret_cast<const float4*>(wzp + k);
      float4 wn = *reinterpret_cast<const float4*>(wnp + k);
      #pragma unroll
      for(int w=0;w<16;w++){
        float4 hv = *reinterpret_cast<const float4*>(&hsh[w][k]);
        ar[w] = fmaf(hv.x,wr.x, fmaf(hv.y,wr.y, fmaf(hv.z,wr.z, fmaf(hv.w,wr.w, ar[w]))));
        az[w] = fmaf(hv.x,wz.x, fmaf(hv.y,wz.y, fmaf(hv.z,wz.z, fmaf(hv.w,wz.w, az[w]))));
        an[w] = fmaf(hv.x,wn.x, fmaf(hv.y,wn.y, fmaf(hv.z,wn.z, fmaf(hv.w,wn.w, an[w]))));
      }
    }
    __syncthreads();
    #pragma unroll
    for(int w=0;w<16;w++){
      const float* u = U2 + (size_t)chsh[w]*G3C;
      float r = sigmoidf_(u[tid]        + ar[w]);
      float z = sigmoidf_(u[CHc+tid]    + az[w]);
      float n = tanhf_   (u[2*CHc+tid]  + r*(an[w] + bhn));
      float hp = hsh[w][tid];
      hsh[w][tid] = (1.f - z)*n + z*hp;
    }
  }
  __syncthreads();
  #pragma unroll
  for(int w=0;w<16;w++) char_h[(size_t)(w0+w)*CHc + tid] = hsh[w][tid];
}

// ---------------------------------------------------------------------------
// K3: gx GEMM, M=4096 tokens, N=1536, K=768; 128x96 tiles; ROW-MAJOR output
// gx[token][g] with bias folded (+bhh for r,z gates).
__global__ __launch_bounds__(256) void k_gxmain(
    const int* __restrict__ x, const float* __restrict__ wemb,
    const float* __restrict__ chh, const float* __restrict__ WihT,
    const float* __restrict__ bih, const float* __restrict__ bhh,
    float* __restrict__ gx){
  __shared__ float As[128][20];
  __shared__ float Bs[16][100];
  __shared__ int xs[128];
  const int tid = threadIdx.x;
  const int rb = blockIdx.x * 128;
  const int nb = blockIdx.y * 96;
  if(tid < 128) xs[tid] = x[rb + tid];
  const int tr = tid >> 4, tc = tid & 15;
  float acc[8][6];
  #pragma unroll
  for(int i=0;i<8;i++)
    #pragma unroll
    for(int j=0;j<6;j++) acc[i][j]=0.f;
  __syncthreads();
  for(int kb=0; kb<KIN; kb+=16){
    #pragma unroll
    for(int i=0;i<2;i++){
      int idx = i*256 + tid;
      int m = idx & 127, kq = idx >> 7;
      int k = kb + kq*4;
      float4 v;
      if(k < EE) v = *reinterpret_cast<const float4*>(&wemb[(size_t)xs[m]*EE + k]);
      else       v = *reinterpret_cast<const float4*>(&chh[(size_t)(rb+m)*CHc + (k-EE)]);
      *reinterpret_cast<float4*>(&As[m][kq*4]) = v;
    }
    #pragma unroll
    for(int i=0;i<2;i++){
      int idx = i*256 + tid;
      if(idx < 384){
        int k = idx / 24, n4 = (idx % 24)*4;
        *reinterpret_cast<float4*>(&Bs[k][n4]) =
            *reinterpret_cast<const float4*>(&WihT[(size_t)(kb+k)*G3H + nb + n4]);
      }
    }
    __syncthreads();
    #pragma unroll
    for(int k=0;k<16;k++){
      float a[8];
      #pragma unroll
      for(int i=0;i<4;i++){ a[i]=As[tr*4+i][k]; a[4+i]=As[64+tr*4+i][k]; }
      float2 b0 = *reinterpret_cast<const float2*>(&Bs[k][tc*2]);
      float2 b1 = *reinterpret_cast<const float2*>(&Bs[k][32+tc*2]);
      float2 b2 = *reinterpret_cast<const float2*>(&Bs[k][64+tc*2]);
      float b[6] = {b0.x,b0.y,b1.x,b1.y,b2.x,b2.y};
      #pragma unroll
      for(int i=0;i<8;i++)
        #pragma unroll
        for(int j=0;j<6;j++)
          acc[i][j] = fmaf(a[i], b[j], acc[i][j]);
    }
    __syncthreads();
  }
  #pragma unroll
  for(int i=0;i<8;i++){
    int row = rb + ((i<4) ? tr*4+i : 64 + tr*4 + (i-4));
    #pragma unroll
    for(int j=0;j<6;j++){
      int g = nb + (j>>1)*32 + tc*2 + (j&1);
      float v = acc[i][j] + bih[g] + (g < 2*HHm ? bhh[g] : 0.f);
      gx[(size_t)row*G3H + g] = v;
    }
  }
}

// ---------------------------------------------------------------------------
// K4 v3: main GRU with producer/consumer flags (NO global barrier).
// 128 blocks = (jb 16) x (bb 8): block owns j-cols [jb*32,+32) x batch rows
// [bb*8,+8). 512 threads = 8 waves; wave kw owns k-slice [kw*64,+64);
// lane = (jp 32, bh 2: 4 batch rows each).
// h state lives directly in outh[t][b][j], exchanged via RELAXED AGENT atomics
// (coherent-point access; no fences -> caches with weights stay warm).
// Writer ordering: atomic_exchange result consumed (vmcnt drain) ->
// __syncthreads -> one flag store per block. Consumer: poll 16 producer flags
// (parallel lanes, separate cache lines; monotonic -> no deadlock) -> stage.
__global__ __launch_bounds__(512) void k_grumain(
    const float* __restrict__ Whh, const float* __restrict__ gx,
    const float* __restrict__ bhh, float* __restrict__ outh,
    int* __restrict__ flags){
  __shared__ float hsh[8][516];      // 16.5KB  h_{t-1}[b][k] padded
  __shared__ float red[24][32][9];   // 27.6KB  [gate*8+b][jp][kw] pad 9 (conflict-free)
  const int tid  = threadIdx.x;
  const int lane = tid & 63;
  const int kw   = tid >> 6;          // 0..7
  const int jp   = lane & 31;
  const int bh   = lane >> 5;         // 0..1
  const int jb   = blockIdx.x & 15;   // 0..15
  const int bb   = blockIdx.x >> 4;   // 0..7
  const int jglob = jb*32 + jp;
  const float* wR = Whh + (size_t)(0*HHm + jglob)*HHm;
  const float* wZ = Whh + (size_t)(1*HHm + jglob)*HHm;
  const float* wN = Whh + (size_t)(2*HHm + jglob)*HHm;
  const int k0 = kw*64;
  // finalize-role mapping (tid<256): b = tid>>5, j2 = tid&31
  const int fb  = tid >> 5;
  const int fj  = tid & 31;
  const int fjg = jb*32 + fj;
  const int fbg = bb*8 + fb;
  const float fbhn = bhh[2*HHm + fjg];

  for(int t=0; t<TT; t++){
    // prefetch gx for this step early (independent of h) to hide poll latency
    float gxr=0.f, gxz=0.f, gxn=0.f;
    if(tid < 256){
      const size_t tok = (size_t)fbg*TT + t;
      gxr = gx[tok*G3H +           fjg];
      gxz = gx[tok*G3H + HHm +     fjg];
      gxn = gx[tok*G3H + 2*HHm +   fjg];
    }
    if(t > 0){
      // wait for the 16 producers of batch-slice bb at step t-1
      if(tid < 16){
        const int* fl = &flags[(((t-1)*8 + bb)*16 + tid)*4];
        while(!__hip_atomic_load(fl, __ATOMIC_RELAXED, __HIP_MEMORY_SCOPE_AGENT))
          __builtin_amdgcn_s_sleep(1);
      }
      __syncthreads();
      // stage h_{t-1}[bb*8..+8)[0..512) via coherent loads
      #pragma unroll
      for(int i=0;i<8;i++){
        int f = i*512 + tid;
        int b = f >> 9, k = f & 511;
        hsh[b][k] = __hip_atomic_load(&outh[((size_t)(t-1)*BB + bb*8 + b)*HHm + k],
                                      __ATOMIC_RELAXED, __HIP_MEMORY_SCOPE_AGENT);
      }
      __syncthreads();
      // dot: wave kw's k-slice, lane (jp, bh) covers 4 batch rows
      float aR[4], aZ[4], aN[4];
      #pragma unroll
      for(int i=0;i<4;i++){ aR[i]=0.f; aZ[i]=0.f; aN[i]=0.f; }
      for(int kk=k0; kk<k0+64; kk+=4){
        float4 r4 = *reinterpret_cast<const float4*>(wR + kk);
        float4 z4 = *reinterpret_cast<const float4*>(wZ + kk);
        float4 n4 = *reinterpret_cast<const float4*>(wN + kk);
        #pragma unroll
        for(int bi=0; bi<4; bi++){
          float4 h4 = *reinterpret_cast<const float4*>(&hsh[bh*4 + bi][kk]);
          aR[bi] = fmaf(h4.x,r4.x, fmaf(h4.y,r4.y, fmaf(h4.z,r4.z, fmaf(h4.w,r4.w, aR[bi]))));
          aZ[bi] = fmaf(h4.x,z4.x, fmaf(h4.y,z4.y, fmaf(h4.z,z4.z, fmaf(h4.w,z4.w, aZ[bi]))));
          aN[bi] = fmaf(h4.x,n4.x, fmaf(h4.y,n4.y, fmaf(h4.z,n4.z, fmaf(h4.w,n4.w, aN[bi]))));
        }
      }
      #pragma unroll
      for(int bi=0;bi<4;bi++){
        int b = bh*4 + bi;
        red[0*8 + b][jp][kw] = aR[bi];
        red[1*8 + b][jp][kw] = aZ[bi];
        red[2*8 + b][jp][kw] = aN[bi];
      }
      __syncthreads();
    }
    // finalize (tid<256): sum 8 wave-partials, gates, write h_t
    if(tid < 256){
      float sR=0.f, sZ=0.f, sN=0.f, hold=0.f;
      if(t > 0){
        #pragma unroll
        for(int w=0; w<8; w++){
          sR += red[0*8+fb][fj][w];
          sZ += red[1*8+fb][fj][w];
          sN += red[2*8+fb][fj][w];
        }
        hold = hsh[fb][fjg];
      }
      float rg = sigmoidf_(gxr + sR);
      float zg = sigmoidf_(gxz + sZ);
      float ng = tanhf_   (gxn + rg*(sN + fbhn));
      float hnew = (1.f - zg)*ng + zg*hold;
      // coherent-point RMW; consuming 'old' forces wait-for-completion
      float old = __hip_atomic_exchange(&outh[((size_t)t*BB + fbg)*HHm + fjg], hnew,
                                        __ATOMIC_RELAXED, __HIP_MEMORY_SCOPE_AGENT);
      asm volatile("" :: "v"(old));
    }
    __syncthreads();    // all exchanges of this block completed at coherence point
    if(t < TT-1 && tid == 0){
      __hip_atomic_store(&flags[((t*8 + bb)*16 + jb)*4], 1,
                         __ATOMIC_RELAXED, __HIP_MEMORY_SCOPE_AGENT);
    }
    // red/hsh reuse protected: next iteration's stage writes hsh after a
    // __syncthreads (t>0 path), red written after another __syncthreads.
  }
}

// ---------------------------------------------------------------------------
// K5: classifier. One block per time-step t; reads outh[t][b][j].
__global__ __launch_bounds__(256) void k_cls(
    const float* __restrict__ outh, const float* __restrict__ clsW,
    const float* __restrict__ clsb, float* __restrict__ out){
  __shared__ float wls[20*HHm];     // 40KB (padded 18->20 rows)
  __shared__ float hch[64][129];    // 33KB  [b][k], stride 129 -> conflict-free
  const int tid = threadIdx.x;
  const int t = blockIdx.x;
  const int b = tid & 63;
  const int q = tid >> 6;
  const int c0 = q*5;
  for(int f = tid*4; f < 20*HHm; f += 1024){
    float4 v = make_float4(0.f,0.f,0.f,0.f);
    if(f < NCLS*HHm) v = *reinterpret_cast<const float4*>(&clsW[f]);
    *reinterpret_cast<float4*>(&wls[f]) = v;
  }
  float acc[5] = {0.f,0.f,0.f,0.f,0.f};
  for(int kc=0; kc<4; kc++){
    __syncthreads();
    for(int i=0;i<32;i++){
      int f = i*256 + tid;            // full coverage of 64x128 chunk
      int b2 = f >> 7, kk = f & 127;
      hch[b2][kk] = outh[((size_t)t*BB + b2)*HHm + kc*128 + kk];
    }
    __syncthreads();
    for(int k=0;k<128;k++){
      float hv = hch[b][k];
      #pragma unroll
      for(int i=0;i<5;i++)
        acc[i] = fmaf(hv, wls[(size_t)(c0+i)*HHm + kc*128 + k], acc[i]);
    }
  }
  #pragma unroll
  for(int i=0;i<5;i++){
    int cls = c0 + i;
    if(cls < NCLS) out[((size_t)b*TT + t)*NCLS + cls] = acc[i] + clsb[cls];
  }
}

// ---------------------------------------------------------------------------
extern "C" void kernel_launch(void* const* d_in, const int* in_sizes, int n_in,
                              void* d_out, int out_size, void* d_ws, size_t ws_size,
                              hipStream_t stream){
  const int*   x     = (const int*)d_in[0];
  const int*   chars = (const int*)d_in[1];
  const float* wemb  = (const float*)d_in[2];
  const float* cemb  = (const float*)d_in[3];
  const float* cWih  = (const float*)d_in[4];
  const float* cWhh  = (const float*)d_in[5];
  const float* cbih  = (const float*)d_in[6];
  const float* cbhh  = (const float*)d_in[7];
  const float* gWih  = (const float*)d_in[8];
  const float* gWhh  = (const float*)d_in[9];
  const float* gbih  = (const float*)d_in[10];
  const float* gbhh  = (const float*)d_in[11];
  const float* clsW  = (const float*)d_in[12];
  const float* clsb  = (const float*)d_in[13];
  float* out = (float*)d_out;
  float* ws  = (float*)d_ws;

  // workspace layout (floats)
  float* U2    = ws;                   // 100*768    = 76800
  float* WihTm = U2 + 76800;           // 768*1536   = 1179648
  float* chh   = WihTm + 1179648;      // 4096*256   = 1048576
  float* gx    = chh + 1048576;        // 4096*1536  = 6291456   [token][g]
  float* outh  = gx + 6291456;         // 64*64*512  = 2097152   [t][b][j]
  int*   flags = (int*)(outh + 2097152); // 64*8*16*4 ints = 32768 (128KB)

  hipMemsetAsync(flags, 0, 64*8*16*4*sizeof(int), stream);
  k_uchar<<<CVOC, G3C, 0, stream>>>(cemb, cWih, cbih, cbhh, U2);
  k_transpose<<<(G3H*KIN + 255)/256, 256, 0, stream>>>(gWih, WihTm, G3H, KIN);
  k_chargru<<<NTOK/16, 256, 0, stream>>>(chars, U2, cWhh, cbhh, chh);
  k_gxmain<<<dim3(NTOK/128, G3H/96), 256, 0, stream>>>(x, wemb, chh, WihTm, gbih, gbhh, gx);
  k_grumain<<<128, 512, 0, stream>>>(gWhh, gx, gbhh, outh, flags);
  k_cls<<<TT, 256, 0, stream>>>(outh, clsW, clsb, out);
}

// Round 6
// 1287.851 us; speedup vs baseline: 2.6817x; 1.3979x over previous
//
#include <hip/hip_runtime.h>
#include <math.h>

// Problem constants
constexpr int CVOC = 100;
constexpr int NCLS = 18;
constexpr int EE   = 512;   // word emb
constexpr int HHm  = 512;   // main GRU hidden
constexpr int CEc  = 128;   // char emb
constexpr int CHc  = 256;   // char GRU hidden
constexpr int BB   = 64;
constexpr int TT   = 64;
constexpr int CCh  = 16;    // chars per word
constexpr int NTOK = BB*TT;       // 4096
constexpr int G3C  = 3*CHc;       // 768
constexpr int G3H  = 3*HHm;       // 1536
constexpr int KIN  = EE + CHc;    // 768

__device__ __forceinline__ float sigmoidf_(float x){ return 1.0f/(1.0f + __expf(-x)); }
__device__ __forceinline__ float tanhf_(float x){ return 1.0f - 2.0f/(__expf(2.0f*x) + 1.0f); }

// ---------------------------------------------------------------------------
// K1: char input-projection table U2[c][g] = char_emb_W[c] . char_Wih[g] + bih[g]
//     (+ bhh[g] folded for r,z gates only)
__global__ void k_uchar(const float* __restrict__ cemb, const float* __restrict__ wih,
                        const float* __restrict__ bih, const float* __restrict__ bhh,
                        float* __restrict__ U2){
  const int c = blockIdx.x;        // 0..99
  const int g = threadIdx.x;       // 0..767
  const float* a = cemb + (size_t)c*CEc;
  const float* w = wih  + (size_t)g*CEc;
  float s = 0.f;
  for(int k=0;k<CEc;k++) s = fmaf(a[k], w[k], s);
  s += bih[g];
  if(g < 2*CHc) s += bhh[g];
  U2[(size_t)c*G3C + g] = s;
}

// ---------------------------------------------------------------------------
// generic transpose: in[R][C] -> out[C][R]
__global__ void k_transpose(const float* __restrict__ in, float* __restrict__ out,
                            int R, int C){
  int idx = blockIdx.x*blockDim.x + threadIdx.x;
  if(idx >= R*C) return;
  int k = idx / R;
  int j = idx % R;
  out[idx] = in[(size_t)j*C + k];
}

// ---------------------------------------------------------------------------
// K2: char GRU. 16 words per 256-thread block. thread = h-column.
__global__ __launch_bounds__(256) void k_chargru(
    const int* __restrict__ chars, const float* __restrict__ U2,
    const float* __restrict__ Whh, const float* __restrict__ bhh,
    float* __restrict__ char_h){
  __shared__ float hsh[16][CHc];    // 16KB
  __shared__ int chsh[16];
  const int tid = threadIdx.x;
  const int w0 = blockIdx.x * 16;
  const float bhn = bhh[2*CHc + tid];
  const float* wrp = Whh + (size_t)tid*CHc;            // gate r row = tid
  const float* wzp = Whh + (size_t)(CHc + tid)*CHc;    // gate z
  const float* wnp = Whh + (size_t)(2*CHc + tid)*CHc;  // gate n
  #pragma unroll
  for(int w=0; w<16; w++) hsh[w][tid] = 0.f;
  for(int t=0; t<CCh; t++){
    __syncthreads();
    if(tid < 16) chsh[tid] = chars[(size_t)(w0 + tid)*CCh + t];
    __syncthreads();
    float ar[16], az[16], an[16];
    #pragma unroll
    for(int w=0;w<16;w++){ ar[w]=0.f; az[w]=0.f; an[w]=0.f; }
    #pragma unroll 2
    for(int k=0; k<CHc; k+=4){
      float4 wr = *reinterpret_cast<const float4*>(wrp + k);
      float4 wz = *reinterpret_cast<const float4*>(wzp + k);
      float4 wn = *reinterpret_cast<const float4*>(wnp + k);
      #pragma unroll
      for(int w=0;w<16;w++){
        float4 hv = *reinterpret_cast<const float4*>(&hsh[w][k]);
        ar[w] = fmaf(hv.x,wr.x, fmaf(hv.y,wr.y, fmaf(hv.z,wr.z, fmaf(hv.w,wr.w, ar[w]))));
        az[w] = fmaf(hv.x,wz.x, fmaf(hv.y,wz.y, fmaf(hv.z,wz.z, fmaf(hv.w,wz.w, az[w]))));
        an[w] = fmaf(hv.x,wn.x, fmaf(hv.y,wn.y, fmaf(hv.z,wn.z, fmaf(hv.w,wn.w, an[w]))));
      }
    }
    __syncthreads();
    #pragma unroll
    for(int w=0;w<16;w++){
      const float* u = U2 + (size_t)chsh[w]*G3C;
      float r = sigmoidf_(u[tid]        + ar[w]);
      float z = sigmoidf_(u[CHc+tid]    + az[w]);
      float n = tanhf_   (u[2*CHc+tid]  + r*(an[w] + bhn));
      float hp = hsh[w][tid];
      hsh[w][tid] = (1.f - z)*n + z*hp;
    }
  }
  __syncthreads();
  #pragma unroll
  for(int w=0;w<16;w++) char_h[(size_t)(w0+w)*CHc + tid] = hsh[w][tid];
}

// ---------------------------------------------------------------------------
// K3: gx GEMM, M=4096 tokens, N=1536, K=768; 128x96 tiles; ROW-MAJOR output
// gx[token][g] with bias folded (+bhh for r,z gates).
__global__ __launch_bounds__(256) void k_gxmain(
    const int* __restrict__ x, const float* __restrict__ wemb,
    const float* __restrict__ chh, const float* __restrict__ WihT,
    const float* __restrict__ bih, const float* __restrict__ bhh,
    float* __restrict__ gx){
  __shared__ float As[128][20];
  __shared__ float Bs[16][100];
  __shared__ int xs[128];
  const int tid = threadIdx.x;
  const int rb = blockIdx.x * 128;
  const int nb = blockIdx.y * 96;
  if(tid < 128) xs[tid] = x[rb + tid];
  const int tr = tid >> 4, tc = tid & 15;
  float acc[8][6];
  #pragma unroll
  for(int i=0;i<8;i++)
    #pragma unroll
    for(int j=0;j<6;j++) acc[i][j]=0.f;
  __syncthreads();
  for(int kb=0; kb<KIN; kb+=16){
    #pragma unroll
    for(int i=0;i<2;i++){
      int idx = i*256 + tid;
      int m = idx & 127, kq = idx >> 7;
      int k = kb + kq*4;
      float4 v;
      if(k < EE) v = *reinterpret_cast<const float4*>(&wemb[(size_t)xs[m]*EE + k]);
      else       v = *reinterpret_cast<const float4*>(&chh[(size_t)(rb+m)*CHc + (k-EE)]);
      *reinterpret_cast<float4*>(&As[m][kq*4]) = v;
    }
    #pragma unroll
    for(int i=0;i<2;i++){
      int idx = i*256 + tid;
      if(idx < 384){
        int k = idx / 24, n4 = (idx % 24)*4;
        *reinterpret_cast<float4*>(&Bs[k][n4]) =
            *reinterpret_cast<const float4*>(&WihT[(size_t)(kb+k)*G3H + nb + n4]);
      }
    }
    __syncthreads();
    #pragma unroll
    for(int k=0;k<16;k++){
      float a[8];
      #pragma unroll
      for(int i=0;i<4;i++){ a[i]=As[tr*4+i][k]; a[4+i]=As[64+tr*4+i][k]; }
      float2 b0 = *reinterpret_cast<const float2*>(&Bs[k][tc*2]);
      float2 b1 = *reinterpret_cast<const float2*>(&Bs[k][32+tc*2]);
      float2 b2 = *reinterpret_cast<const float2*>(&Bs[k][64+tc*2]);
      float b[6] = {b0.x,b0.y,b1.x,b1.y,b2.x,b2.y};
      #pragma unroll
      for(int i=0;i<8;i++)
        #pragma unroll
        for(int j=0;j<6;j++)
          acc[i][j] = fmaf(a[i], b[j], acc[i][j]);
    }
    __syncthreads();
  }
  #pragma unroll
  for(int i=0;i<8;i++){
    int row = rb + ((i<4) ? tr*4+i : 64 + tr*4 + (i-4));
    #pragma unroll
    for(int j=0;j<6;j++){
      int g = nb + (j>>1)*32 + tc*2 + (j&1);
      float v = acc[i][j] + bih[g] + (g < 2*HHm ? bhh[g] : 0.f);
      gx[(size_t)row*G3H + g] = v;
    }
  }
}

// ---------------------------------------------------------------------------
// K4 v4: main GRU, REGISTER-STATIONARY weights + producer/consumer flags.
// 256 blocks = (jb 32) x (bb 8): block owns j [jb*16,+16) x batch [bb*8,+8).
// 512 threads: wave kw (8) = k-slice 64; lane = (jp 16, bq 4) -> thread covers
// k-chunk [kw*64+bq*16,+16) for j=jb*16+jp, ALL 8 batch rows.
// Weights (3 gates x 16 k = 12 float4) loaded ONCE into VGPRs before t-loop:
// per-step traffic is only h (16KB agent loads) + gx (1.5KB) + partial reduce.
// Reduce: cross-bq via shfl_xor (lanes 16,32), cross-kw via small LDS array.
__global__ __launch_bounds__(512) void k_grumain(
    const float* __restrict__ Whh, const float* __restrict__ gx,
    const float* __restrict__ bhh, float* __restrict__ outh,
    int* __restrict__ flags){
  __shared__ float hsh[8][516];      // 16.5KB  h_{t-1}[b][k] padded (516%32=4)
  __shared__ float red[3][8][16][9]; // 13.8KB  [gate][b][jp][kw] pad 9
  const int tid  = threadIdx.x;
  const int lane = tid & 63;
  const int kw   = tid >> 6;          // 0..7
  const int jp   = lane & 15;
  const int bq   = lane >> 4;         // 0..3
  const int jb   = blockIdx.x & 31;   // 0..31
  const int bb   = blockIdx.x >> 5;   // 0..7
  const int jglob = jb*16 + jp;
  const int kbase = kw*64 + bq*16;
  // ---- one-time: weights into registers (invariant over all 64 steps) ----
  float4 wreg[3][4];
  #pragma unroll
  for(int g=0; g<3; g++)
    #pragma unroll
    for(int q=0; q<4; q++)
      wreg[g][q] = *reinterpret_cast<const float4*>(
          &Whh[((size_t)g*HHm + jglob)*HHm + kbase + q*4]);
  // finalize-role mapping (tid<128): fb = tid>>4, fj = tid&15
  const int fb  = tid >> 4;
  const int fj  = tid & 15;
  const int fjg = jb*16 + fj;
  const int fbg = bb*8 + fb;
  const float fbhn = bhh[2*HHm + fjg];

  for(int t=0; t<TT; t++){
    // prefetch gx early (independent of h)
    float gxr=0.f, gxz=0.f, gxn=0.f;
    if(tid < 128){
      const size_t tok = (size_t)fbg*TT + t;
      gxr = gx[tok*G3H +           fjg];
      gxz = gx[tok*G3H + HHm +     fjg];
      gxn = gx[tok*G3H + 2*HHm +   fjg];
    }
    if(t > 0){
      // wait for the 32 producers of batch-slice bb at step t-1
      if(tid < 32){
        const int* fl = &flags[(((t-1)*8 + bb)*32 + tid)*16];
        while(!__hip_atomic_load(fl, __ATOMIC_RELAXED, __HIP_MEMORY_SCOPE_AGENT))
          __builtin_amdgcn_s_sleep(1);
      }
      __syncthreads();
      // stage h_{t-1}[bb*8..+8)[0..512) : coherent agent loads, coalesced
      #pragma unroll
      for(int i=0;i<8;i++){
        int f = i*512 + tid;
        int b = f >> 9, k = f & 511;
        hsh[b][k] = __hip_atomic_load(&outh[((size_t)(t-1)*BB + bb*8 + b)*HHm + k],
                                      __ATOMIC_RELAXED, __HIP_MEMORY_SCOPE_AGENT);
      }
      __syncthreads();
      // dot from registers + LDS broadcasts
      float aR[8], aZ[8], aN[8];
      #pragma unroll
      for(int b=0;b<8;b++){ aR[b]=0.f; aZ[b]=0.f; aN[b]=0.f; }
      #pragma unroll
      for(int b=0; b<8; b++){
        float4 h0 = *reinterpret_cast<const float4*>(&hsh[b][kbase+0]);
        float4 h1 = *reinterpret_cast<const float4*>(&hsh[b][kbase+4]);
        float4 h2 = *reinterpret_cast<const float4*>(&hsh[b][kbase+8]);
        float4 h3 = *reinterpret_cast<const float4*>(&hsh[b][kbase+12]);
        aR[b] = fmaf(h0.x,wreg[0][0].x, fmaf(h0.y,wreg[0][0].y, fmaf(h0.z,wreg[0][0].z, fmaf(h0.w,wreg[0][0].w, aR[b]))));
        aR[b] = fmaf(h1.x,wreg[0][1].x, fmaf(h1.y,wreg[0][1].y, fmaf(h1.z,wreg[0][1].z, fmaf(h1.w,wreg[0][1].w, aR[b]))));
        aR[b] = fmaf(h2.x,wreg[0][2].x, fmaf(h2.y,wreg[0][2].y, fmaf(h2.z,wreg[0][2].z, fmaf(h2.w,wreg[0][2].w, aR[b]))));
        aR[b] = fmaf(h3.x,wreg[0][3].x, fmaf(h3.y,wreg[0][3].y, fmaf(h3.z,wreg[0][3].z, fmaf(h3.w,wreg[0][3].w, aR[b]))));
        aZ[b] = fmaf(h0.x,wreg[1][0].x, fmaf(h0.y,wreg[1][0].y, fmaf(h0.z,wreg[1][0].z, fmaf(h0.w,wreg[1][0].w, aZ[b]))));
        aZ[b] = fmaf(h1.x,wreg[1][1].x, fmaf(h1.y,wreg[1][1].y, fmaf(h1.z,wreg[1][1].z, fmaf(h1.w,wreg[1][1].w, aZ[b]))));
        aZ[b] = fmaf(h2.x,wreg[1][2].x, fmaf(h2.y,wreg[1][2].y, fmaf(h2.z,wreg[1][2].z, fmaf(h2.w,wreg[1][2].w, aZ[b]))));
        aZ[b] = fmaf(h3.x,wreg[1][3].x, fmaf(h3.y,wreg[1][3].y, fmaf(h3.z,wreg[1][3].z, fmaf(h3.w,wreg[1][3].w, aZ[b]))));
        aN[b] = fmaf(h0.x,wreg[2][0].x, fmaf(h0.y,wreg[2][0].y, fmaf(h0.z,wreg[2][0].z, fmaf(h0.w,wreg[2][0].w, aN[b]))));
        aN[b] = fmaf(h1.x,wreg[2][1].x, fmaf(h1.y,wreg[2][1].y, fmaf(h1.z,wreg[2][1].z, fmaf(h1.w,wreg[2][1].w, aN[b]))));
        aN[b] = fmaf(h2.x,wreg[2][2].x, fmaf(h2.y,wreg[2][2].y, fmaf(h2.z,wreg[2][2].z, fmaf(h2.w,wreg[2][2].w, aN[b]))));
        aN[b] = fmaf(h3.x,wreg[2][3].x, fmaf(h3.y,wreg[2][3].y, fmaf(h3.z,wreg[2][3].z, fmaf(h3.w,wreg[2][3].w, aN[b]))));
      }
      // cross-bq reduce: lanes differing in bits 4,5 hold the 4 k-sub-chunks
      #pragma unroll
      for(int b=0;b<8;b++){
        aR[b] += __shfl_xor(aR[b], 16, 64); aR[b] += __shfl_xor(aR[b], 32, 64);
        aZ[b] += __shfl_xor(aZ[b], 16, 64); aZ[b] += __shfl_xor(aZ[b], 32, 64);
        aN[b] += __shfl_xor(aN[b], 16, 64); aN[b] += __shfl_xor(aN[b], 32, 64);
      }
      // lane bq writes b = {bq*2, bq*2+1} partials to LDS (per-kw slot)
      #pragma unroll
      for(int i=0;i<2;i++){
        int b = bq*2 + i;
        red[0][b][jp][kw] = aR[b];
        red[1][b][jp][kw] = aZ[b];
        red[2][b][jp][kw] = aN[b];
      }
      __syncthreads();
    }
    // finalize (tid<128): sum 8 kw-partials, gates, write h_t
    if(tid < 128){
      float sR=0.f, sZ=0.f, sN=0.f, hold=0.f;
      if(t > 0){
        #pragma unroll
        for(int w=0; w<8; w++){
          sR += red[0][fb][fj][w];
          sZ += red[1][fb][fj][w];
          sN += red[2][fb][fj][w];
        }
        hold = hsh[fb][fjg];
      }
      float rg = sigmoidf_(gxr + sR);
      float zg = sigmoidf_(gxz + sZ);
      float ng = tanhf_   (gxn + rg*(sN + fbhn));
      float hnew = (1.f - zg)*ng + zg*hold;
      // coherent-point RMW; consuming 'old' forces wait-for-completion
      float old = __hip_atomic_exchange(&outh[((size_t)t*BB + fbg)*HHm + fjg], hnew,
                                        __ATOMIC_RELAXED, __HIP_MEMORY_SCOPE_AGENT);
      asm volatile("" :: "v"(old));
    }
    __syncthreads();    // all exchanges completed at coherence point
    if(t < TT-1 && tid == 0){
      __hip_atomic_store(&flags[((t*8 + bb)*32 + jb)*16], 1,
                         __ATOMIC_RELAXED, __HIP_MEMORY_SCOPE_AGENT);
    }
  }
}

// ---------------------------------------------------------------------------
// K5: classifier. One block per time-step t; reads outh[t][b][j].
__global__ __launch_bounds__(256) void k_cls(
    const float* __restrict__ outh, const float* __restrict__ clsW,
    const float* __restrict__ clsb, float* __restrict__ out){
  __shared__ float wls[20*HHm];     // 40KB (padded 18->20 rows)
  __shared__ float hch[64][129];    // 33KB  [b][k], stride 129 -> conflict-free
  const int tid = threadIdx.x;
  const int t = blockIdx.x;
  const int b = tid & 63;
  const int q = tid >> 6;
  const int c0 = q*5;
  for(int f = tid*4; f < 20*HHm; f += 1024){
    float4 v = make_float4(0.f,0.f,0.f,0.f);
    if(f < NCLS*HHm) v = *reinterpret_cast<const float4*>(&clsW[f]);
    *reinterpret_cast<float4*>(&wls[f]) = v;
  }
  float acc[5] = {0.f,0.f,0.f,0.f,0.f};
  for(int kc=0; kc<4; kc++){
    __syncthreads();
    for(int i=0;i<32;i++){
      int f = i*256 + tid;            // full coverage of 64x128 chunk
      int b2 = f >> 7, kk = f & 127;
      hch[b2][kk] = outh[((size_t)t*BB + b2)*HHm + kc*128 + kk];
    }
    __syncthreads();
    for(int k=0;k<128;k++){
      float hv = hch[b][k];
      #pragma unroll
      for(int i=0;i<5;i++)
        acc[i] = fmaf(hv, wls[(size_t)(c0+i)*HHm + kc*128 + k], acc[i]);
    }
  }
  #pragma unroll
  for(int i=0;i<5;i++){
    int cls = c0 + i;
    if(cls < NCLS) out[((size_t)b*TT + t)*NCLS + cls] = acc[i] + clsb[cls];
  }
}

// ---------------------------------------------------------------------------
extern "C" void kernel_launch(void* const* d_in, const int* in_sizes, int n_in,
                              void* d_out, int out_size, void* d_ws, size_t ws_size,
                              hipStream_t stream){
  const int*   x     = (const int*)d_in[0];
  const int*   chars = (const int*)d_in[1];
  const float* wemb  = (const float*)d_in[2];
  const float* cemb  = (const float*)d_in[3];
  const float* cWih  = (const float*)d_in[4];
  const float* cWhh  = (const float*)d_in[5];
  const float* cbih  = (const float*)d_in[6];
  const float* cbhh  = (const float*)d_in[7];
  const float* gWih  = (const float*)d_in[8];
  const float* gWhh  = (const float*)d_in[9];
  const float* gbih  = (const float*)d_in[10];
  const float* gbhh  = (const float*)d_in[11];
  const float* clsW  = (const float*)d_in[12];
  const float* clsb  = (const float*)d_in[13];
  float* out = (float*)d_out;
  float* ws  = (float*)d_ws;

  // workspace layout (floats)
  float* U2    = ws;                   // 100*768    = 76800
  float* WihTm = U2 + 76800;           // 768*1536   = 1179648
  float* chh   = WihTm + 1179648;      // 4096*256   = 1048576
  float* gx    = chh + 1048576;        // 4096*1536  = 6291456   [token][g]
  float* outh  = gx + 6291456;         // 64*64*512  = 2097152   [t][b][j]
  int*   flags = (int*)(outh + 2097152); // 64*8*32*16 ints = 262144 (1MB)

  hipMemsetAsync(flags, 0, 64*8*32*16*sizeof(int), stream);
  k_uchar<<<CVOC, G3C, 0, stream>>>(cemb, cWih, cbih, cbhh, U2);
  k_transpose<<<(G3H*KIN + 255)/256, 256, 0, stream>>>(gWih, WihTm, G3H, KIN);
  k_chargru<<<NTOK/16, 256, 0, stream>>>(chars, U2, cWhh, cbhh, chh);
  k_gxmain<<<dim3(NTOK/128, G3H/96), 256, 0, stream>>>(x, wemb, chh, WihTm, gbih, gbhh, gx);
  k_grumain<<<256, 512, 0, stream>>>(gWhh, gx, gbhh, outh, flags);
  k_cls<<<TT, 256, 0, stream>>>(outh, clsW, clsb, out);
}

// Round 7
// 724.079 us; speedup vs baseline: 4.7697x; 1.7786x over previous
//
#include <hip/hip_runtime.h>
#include <math.h>

// Problem constants
constexpr int CVOC = 100;
constexpr int NCLS = 18;
constexpr int EE   = 512;   // word emb
constexpr int HHm  = 512;   // main GRU hidden
constexpr int CEc  = 128;   // char emb
constexpr int CHc  = 256;   // char GRU hidden
constexpr int BB   = 64;
constexpr int TT   = 64;
constexpr int CCh  = 16;    // chars per word
constexpr int NTOK = BB*TT;       // 4096
constexpr int G3C  = 3*CHc;       // 768
constexpr int G3H  = 3*HHm;       // 1536
constexpr int KIN  = EE + CHc;    // 768

typedef __attribute__((ext_vector_type(8))) short bf16x8;
typedef __attribute__((ext_vector_type(4))) float f32x4;

__device__ __forceinline__ float sigmoidf_(float x){ return 1.0f/(1.0f + __expf(-x)); }
__device__ __forceinline__ float tanhf_(float x){ return 1.0f - 2.0f/(__expf(2.0f*x) + 1.0f); }
__device__ __forceinline__ unsigned short f2bf(float x){
  unsigned int u = __float_as_uint(x);
  unsigned int r = (u + 0x7FFFu + ((u>>16)&1u)) >> 16;
  return (unsigned short)r;
}

// ---------------------------------------------------------------------------
// K1: char input-projection table U2[c][g] = char_emb_W[c] . char_Wih[g] + bih[g]
//     (+ bhh[g] folded for r,z gates only). Stays f32 (biases exact).
__global__ void k_uchar(const float* __restrict__ cemb, const float* __restrict__ wih,
                        const float* __restrict__ bih, const float* __restrict__ bhh,
                        float* __restrict__ U2){
  const int c = blockIdx.x;        // 0..99
  const int g = threadIdx.x;       // 0..767
  const float* a = cemb + (size_t)c*CEc;
  const float* w = wih  + (size_t)g*CEc;
  float s = 0.f;
  for(int k=0;k<CEc;k++) s = fmaf(a[k], w[k], s);
  s += bih[g];
  if(g < 2*CHc) s += bhh[g];
  U2[(size_t)c*G3C + g] = s;
}

// ---------------------------------------------------------------------------
// generic transpose: in[R][C] -> out[C][R]
__global__ void k_transpose(const float* __restrict__ in, float* __restrict__ out,
                            int R, int C){
  int idx = blockIdx.x*blockDim.x + threadIdx.x;
  if(idx >= R*C) return;
  int k = idx / R;
  int j = idx % R;
  out[idx] = in[(size_t)j*C + k];
}

// ---------------------------------------------------------------------------
// f32 -> bf16 (RNE) conversion for cWhh [768][256]
__global__ void k_w2bf(const float* __restrict__ in, unsigned short* __restrict__ out,
                       int n){
  int i = blockIdx.x*256 + threadIdx.x;
  if(i < n) out[i] = f2bf(in[i]);
}

// ---------------------------------------------------------------------------
// K2 v3: char GRU via bf16 MFMA (16x16x32, f32 accumulate).
// 256 blocks x 256 threads (4 waves). Block owns 16 words.
// Per step: gh[16 words][768 g] = h_bf16[16][256] @ Wb^T  via MFMA
//   wave wv owns 12 g-tiles (192 cols); 8 k-steps of 32.
// A-frag: lane l = h[word=l&15][ks*32+(l>>4)*8 ..+8]   (LDS b128)
// B-frag: lane l = Wb[g0+(l&15)][ks*32+(l>>4)*8 ..+8]  (global 16B, L2-hot)
// C/D   : lane l reg i -> [word=(l>>4)*4+i][g0+(l&15)] (m89-verified)
// Epilogue in f32: gates from U2 (f32) + gh; h kept f32 (hf) + bf16 (hb).
__global__ __launch_bounds__(256) void k_chargru(
    const int* __restrict__ chars, const float* __restrict__ U2,
    const unsigned short* __restrict__ Wb, const float* __restrict__ bhh,
    float* __restrict__ char_h){
  __shared__ unsigned short hb[16][272];  // 8.7KB  bf16 h (stride 272: 16B-aligned rows)
  __shared__ float hf[16][257];           // 16.4KB f32 h
  __shared__ float ghL[16][771];          // 49.3KB gh staging
  __shared__ int chs[16];
  const int tid  = threadIdx.x;
  const int lane = tid & 63;
  const int wv   = tid >> 6;        // 0..3
  const int la   = lane & 15;       // m/n fragment index
  const int lb   = lane >> 4;       // k-chunk 0..3
  const int w0   = blockIdx.x * 16;
  const float bhn = bhh[2*CHc + tid];   // n-gate bhh for h-col tid
  // zero init h
  #pragma unroll
  for(int w=0; w<16; w++){ hf[w][tid] = 0.f; hb[w][tid] = 0; }

  for(int t=0; t<CCh; t++){
    __syncthreads();                    // hb/hf (t-1) visible; chs (t-1) consumed
    if(tid < 16) chs[tid] = chars[(size_t)(w0 + tid)*CCh + t];
    // ---- MFMA phase: gh = h @ W^T over this wave's 192 g-cols ----
    f32x4 acc[12];
    #pragma unroll
    for(int i=0;i<12;i++) acc[i] = (f32x4){0.f,0.f,0.f,0.f};
    #pragma unroll
    for(int ks=0; ks<8; ks++){
      bf16x8 af = *reinterpret_cast<const bf16x8*>(&hb[la][ks*32 + lb*8]);
      #pragma unroll
      for(int gt=0; gt<12; gt++){
        const int gcol = wv*192 + gt*16 + la;
        bf16x8 bfv = *reinterpret_cast<const bf16x8*>(&Wb[(size_t)gcol*CHc + ks*32 + lb*8]);
        acc[gt] = __builtin_amdgcn_mfma_f32_16x16x32_bf16(af, bfv, acc[gt], 0, 0, 0);
      }
    }
    #pragma unroll
    for(int gt=0; gt<12; gt++){
      const int gcol = wv*192 + gt*16 + la;
      #pragma unroll
      for(int i=0;i<4;i++)
        ghL[lb*4 + i][gcol] = acc[gt][i];
    }
    __syncthreads();                    // ghL + chs ready
    // ---- gate phase (f32): thread = h-col c ----
    {
      const int c = tid;
      #pragma unroll
      for(int w=0; w<16; w++){
        const float* u = U2 + (size_t)chs[w]*G3C;
        float r = sigmoidf_(u[c]         + ghL[w][c]);
        float z = sigmoidf_(u[CHc + c]   + ghL[w][CHc + c]);
        float n = tanhf_   (u[2*CHc + c] + r*(ghL[w][2*CHc + c] + bhn));
        float hp = hf[w][c];
        float hn = (1.f - z)*n + z*hp;
        hf[w][c] = hn;
        hb[w][c] = f2bf(hn);
      }
    }
  }
  __syncthreads();
  #pragma unroll
  for(int w=0; w<16; w++) char_h[(size_t)(w0+w)*CHc + tid] = hf[w][tid];
}

// ---------------------------------------------------------------------------
// K3: gx GEMM, M=4096 tokens, N=1536, K=768; 128x96 tiles; ROW-MAJOR output
// gx[token][g] with bias folded (+bhh for r,z gates).
__global__ __launch_bounds__(256) void k_gxmain(
    const int* __restrict__ x, const float* __restrict__ wemb,
    const float* __restrict__ chh, const float* __restrict__ WihT,
    const float* __restrict__ bih, const float* __restrict__ bhh,
    float* __restrict__ gx){
  __shared__ float As[128][20];
  __shared__ float Bs[16][100];
  __shared__ int xs[128];
  const int tid = threadIdx.x;
  const int rb = blockIdx.x * 128;
  const int nb = blockIdx.y * 96;
  if(tid < 128) xs[tid] = x[rb + tid];
  const int tr = tid >> 4, tc = tid & 15;
  float acc[8][6];
  #pragma unroll
  for(int i=0;i<8;i++)
    #pragma unroll
    for(int j=0;j<6;j++) acc[i][j]=0.f;
  __syncthreads();
  for(int kb=0; kb<KIN; kb+=16){
    #pragma unroll
    for(int i=0;i<2;i++){
      int idx = i*256 + tid;
      int m = idx & 127, kq = idx >> 7;
      int k = kb + kq*4;
      float4 v;
      if(k < EE) v = *reinterpret_cast<const float4*>(&wemb[(size_t)xs[m]*EE + k]);
      else       v = *reinterpret_cast<const float4*>(&chh[(size_t)(rb+m)*CHc + (k-EE)]);
      *reinterpret_cast<float4*>(&As[m][kq*4]) = v;
    }
    #pragma unroll
    for(int i=0;i<2;i++){
      int idx = i*256 + tid;
      if(idx < 384){
        int k = idx / 24, n4 = (idx % 24)*4;
        *reinterpret_cast<float4*>(&Bs[k][n4]) =
            *reinterpret_cast<const float4*>(&WihT[(size_t)(kb+k)*G3H + nb + n4]);
      }
    }
    __syncthreads();
    #pragma unroll
    for(int k=0;k<16;k++){
      float a[8];
      #pragma unroll
      for(int i=0;i<4;i++){ a[i]=As[tr*4+i][k]; a[4+i]=As[64+tr*4+i][k]; }
      float2 b0 = *reinterpret_cast<const float2*>(&Bs[k][tc*2]);
      float2 b1 = *reinterpret_cast<const float2*>(&Bs[k][32+tc*2]);
      float2 b2 = *reinterpret_cast<const float2*>(&Bs[k][64+tc*2]);
      float b[6] = {b0.x,b0.y,b1.x,b1.y,b2.x,b2.y};
      #pragma unroll
      for(int i=0;i<8;i++)
        #pragma unroll
        for(int j=0;j<6;j++)
          acc[i][j] = fmaf(a[i], b[j], acc[i][j]);
    }
    __syncthreads();
  }
  #pragma unroll
  for(int i=0;i<8;i++){
    int row = rb + ((i<4) ? tr*4+i : 64 + tr*4 + (i-4));
    #pragma unroll
    for(int j=0;j<6;j++){
      int g = nb + (j>>1)*32 + tc*2 + (j&1);
      float v = acc[i][j] + bih[g] + (g < 2*HHm ? bhh[g] : 0.f);
      gx[(size_t)row*G3H + g] = v;
    }
  }
}

// ---------------------------------------------------------------------------
// K4 v4: main GRU, REGISTER-STATIONARY weights + producer/consumer flags.
// (unchanged from round 6 — ~405 us; next round's target)
__global__ __launch_bounds__(512) void k_grumain(
    const float* __restrict__ Whh, const float* __restrict__ gx,
    const float* __restrict__ bhh, float* __restrict__ outh,
    int* __restrict__ flags){
  __shared__ float hsh[8][516];      // 16.5KB  h_{t-1}[b][k] padded (516%32=4)
  __shared__ float red[3][8][16][9]; // 13.8KB  [gate][b][jp][kw] pad 9
  const int tid  = threadIdx.x;
  const int lane = tid & 63;
  const int kw   = tid >> 6;          // 0..7
  const int jp   = lane & 15;
  const int bq   = lane >> 4;         // 0..3
  const int jb   = blockIdx.x & 31;   // 0..31
  const int bb   = blockIdx.x >> 5;   // 0..7
  const int jglob = jb*16 + jp;
  const int kbase = kw*64 + bq*16;
  float4 wreg[3][4];
  #pragma unroll
  for(int g=0; g<3; g++)
    #pragma unroll
    for(int q=0; q<4; q++)
      wreg[g][q] = *reinterpret_cast<const float4*>(
          &Whh[((size_t)g*HHm + jglob)*HHm + kbase + q*4]);
  const int fb  = tid >> 4;
  const int fj  = tid & 15;
  const int fjg = jb*16 + fj;
  const int fbg = bb*8 + fb;
  const float fbhn = bhh[2*HHm + fjg];

  for(int t=0; t<TT; t++){
    float gxr=0.f, gxz=0.f, gxn=0.f;
    if(tid < 128){
      const size_t tok = (size_t)fbg*TT + t;
      gxr = gx[tok*G3H +           fjg];
      gxz = gx[tok*G3H + HHm +     fjg];
      gxn = gx[tok*G3H + 2*HHm +   fjg];
    }
    if(t > 0){
      if(tid < 32){
        const int* fl = &flags[(((t-1)*8 + bb)*32 + tid)*16];
        while(!__hip_atomic_load(fl, __ATOMIC_RELAXED, __HIP_MEMORY_SCOPE_AGENT))
          __builtin_amdgcn_s_sleep(1);
      }
      __syncthreads();
      #pragma unroll
      for(int i=0;i<8;i++){
        int f = i*512 + tid;
        int b = f >> 9, k = f & 511;
        hsh[b][k] = __hip_atomic_load(&outh[((size_t)(t-1)*BB + bb*8 + b)*HHm + k],
                                      __ATOMIC_RELAXED, __HIP_MEMORY_SCOPE_AGENT);
      }
      __syncthreads();
      float aR[8], aZ[8], aN[8];
      #pragma unroll
      for(int b=0;b<8;b++){ aR[b]=0.f; aZ[b]=0.f; aN[b]=0.f; }
      #pragma unroll
      for(int b=0; b<8; b++){
        float4 h0 = *reinterpret_cast<const float4*>(&hsh[b][kbase+0]);
        float4 h1 = *reinterpret_cast<const float4*>(&hsh[b][kbase+4]);
        float4 h2 = *reinterpret_cast<const float4*>(&hsh[b][kbase+8]);
        float4 h3 = *reinterpret_cast<const float4*>(&hsh[b][kbase+12]);
        aR[b] = fmaf(h0.x,wreg[0][0].x, fmaf(h0.y,wreg[0][0].y, fmaf(h0.z,wreg[0][0].z, fmaf(h0.w,wreg[0][0].w, aR[b]))));
        aR[b] = fmaf(h1.x,wreg[0][1].x, fmaf(h1.y,wreg[0][1].y, fmaf(h1.z,wreg[0][1].z, fmaf(h1.w,wreg[0][1].w, aR[b]))));
        aR[b] = fmaf(h2.x,wreg[0][2].x, fmaf(h2.y,wreg[0][2].y, fmaf(h2.z,wreg[0][2].z, fmaf(h2.w,wreg[0][2].w, aR[b]))));
        aR[b] = fmaf(h3.x,wreg[0][3].x, fmaf(h3.y,wreg[0][3].y, fmaf(h3.z,wreg[0][3].z, fmaf(h3.w,wreg[0][3].w, aR[b]))));
        aZ[b] = fmaf(h0.x,wreg[1][0].x, fmaf(h0.y,wreg[1][0].y, fmaf(h0.z,wreg[1][0].z, fmaf(h0.w,wreg[1][0].w, aZ[b]))));
        aZ[b] = fmaf(h1.x,wreg[1][1].x, fmaf(h1.y,wreg[1][1].y, fmaf(h1.z,wreg[1][1].z, fmaf(h1.w,wreg[1][1].w, aZ[b]))));
        aZ[b] = fmaf(h2.x,wreg[1][2].x, fmaf(h2.y,wreg[1][2].y, fmaf(h2.z,wreg[1][2].z, fmaf(h2.w,wreg[1][2].w, aZ[b]))));
        aZ[b] = fmaf(h3.x,wreg[1][3].x, fmaf(h3.y,wreg[1][3].y, fmaf(h3.z,wreg[1][3].z, fmaf(h3.w,wreg[1][3].w, aZ[b]))));
        aN[b] = fmaf(h0.x,wreg[2][0].x, fmaf(h0.y,wreg[2][0].y, fmaf(h0.z,wreg[2][0].z, fmaf(h0.w,wreg[2][0].w, aN[b]))));
        aN[b] = fmaf(h1.x,wreg[2][1].x, fmaf(h1.y,wreg[2][1].y, fmaf(h1.z,wreg[2][1].z, fmaf(h1.w,wreg[2][1].w, aN[b]))));
        aN[b] = fmaf(h2.x,wreg[2][2].x, fmaf(h2.y,wreg[2][2].y, fmaf(h2.z,wreg[2][2].z, fmaf(h2.w,wreg[2][2].w, aN[b]))));
        aN[b] = fmaf(h3.x,wreg[2][3].x, fmaf(h3.y,wreg[2][3].y, fmaf(h3.z,wreg[2][3].z, fmaf(h3.w,wreg[2][3].w, aN[b]))));
      }
      #pragma unroll
      for(int b=0;b<8;b++){
        aR[b] += __shfl_xor(aR[b], 16, 64); aR[b] += __shfl_xor(aR[b], 32, 64);
        aZ[b] += __shfl_xor(aZ[b], 16, 64); aZ[b] += __shfl_xor(aZ[b], 32, 64);
        aN[b] += __shfl_xor(aN[b], 16, 64); aN[b] += __shfl_xor(aN[b], 32, 64);
      }
      #pragma unroll
      for(int i=0;i<2;i++){
        int b = bq*2 + i;
        red[0][b][jp][kw] = aR[b];
        red[1][b][jp][kw] = aZ[b];
        red[2][b][jp][kw] = aN[b];
      }
      __syncthreads();
    }
    if(tid < 128){
      float sR=0.f, sZ=0.f, sN=0.f, hold=0.f;
      if(t > 0){
        #pragma unroll
        for(int w=0; w<8; w++){
          sR += red[0][fb][fj][w];
          sZ += red[1][fb][fj][w];
          sN += red[2][fb][fj][w];
        }
        hold = hsh[fb][fjg];
      }
      float rg = sigmoidf_(gxr + sR);
      float zg = sigmoidf_(gxz + sZ);
      float ng = tanhf_   (gxn + rg*(sN + fbhn));
      float hnew = (1.f - zg)*ng + zg*hold;
      float old = __hip_atomic_exchange(&outh[((size_t)t*BB + fbg)*HHm + fjg], hnew,
                                        __ATOMIC_RELAXED, __HIP_MEMORY_SCOPE_AGENT);
      asm volatile("" :: "v"(old));
    }
    __syncthreads();
    if(t < TT-1 && tid == 0){
      __hip_atomic_store(&flags[((t*8 + bb)*32 + jb)*16], 1,
                         __ATOMIC_RELAXED, __HIP_MEMORY_SCOPE_AGENT);
    }
  }
}

// ---------------------------------------------------------------------------
// K5: classifier. One block per time-step t; reads outh[t][b][j].
__global__ __launch_bounds__(256) void k_cls(
    const float* __restrict__ outh, const float* __restrict__ clsW,
    const float* __restrict__ clsb, float* __restrict__ out){
  __shared__ float wls[20*HHm];     // 40KB (padded 18->20 rows)
  __shared__ float hch[64][129];    // 33KB  [b][k], stride 129 -> conflict-free
  const int tid = threadIdx.x;
  const int t = blockIdx.x;
  const int b = tid & 63;
  const int q = tid >> 6;
  const int c0 = q*5;
  for(int f = tid*4; f < 20*HHm; f += 1024){
    float4 v = make_float4(0.f,0.f,0.f,0.f);
    if(f < NCLS*HHm) v = *reinterpret_cast<const float4*>(&clsW[f]);
    *reinterpret_cast<float4*>(&wls[f]) = v;
  }
  float acc[5] = {0.f,0.f,0.f,0.f,0.f};
  for(int kc=0; kc<4; kc++){
    __syncthreads();
    for(int i=0;i<32;i++){
      int f = i*256 + tid;            // full coverage of 64x128 chunk
      int b2 = f >> 7, kk = f & 127;
      hch[b2][kk] = outh[((size_t)t*BB + b2)*HHm + kc*128 + kk];
    }
    __syncthreads();
    for(int k=0;k<128;k++){
      float hv = hch[b][k];
      #pragma unroll
      for(int i=0;i<5;i++)
        acc[i] = fmaf(hv, wls[(size_t)(c0+i)*HHm + kc*128 + k], acc[i]);
    }
  }
  #pragma unroll
  for(int i=0;i<5;i++){
    int cls = c0 + i;
    if(cls < NCLS) out[((size_t)b*TT + t)*NCLS + cls] = acc[i] + clsb[cls];
  }
}

// ---------------------------------------------------------------------------
extern "C" void kernel_launch(void* const* d_in, const int* in_sizes, int n_in,
                              void* d_out, int out_size, void* d_ws, size_t ws_size,
                              hipStream_t stream){
  const int*   x     = (const int*)d_in[0];
  const int*   chars = (const int*)d_in[1];
  const float* wemb  = (const float*)d_in[2];
  const float* cemb  = (const float*)d_in[3];
  const float* cWih  = (const float*)d_in[4];
  const float* cWhh  = (const float*)d_in[5];
  const float* cbih  = (const float*)d_in[6];
  const float* cbhh  = (const float*)d_in[7];
  const float* gWih  = (const float*)d_in[8];
  const float* gWhh  = (const float*)d_in[9];
  const float* gbih  = (const float*)d_in[10];
  const float* gbhh  = (const float*)d_in[11];
  const float* clsW  = (const float*)d_in[12];
  const float* clsb  = (const float*)d_in[13];
  float* out = (float*)d_out;
  float* ws  = (float*)d_ws;

  // workspace layout (floats)
  float* U2    = ws;                   // 100*768    = 76800
  float* WihTm = U2 + 76800;           // 768*1536   = 1179648
  float* chh   = WihTm + 1179648;      // 4096*256   = 1048576
  float* gx    = chh + 1048576;        // 4096*1536  = 6291456   [token][g]
  float* outh  = gx + 6291456;         // 64*64*512  = 2097152   [t][b][j]
  int*   flags = (int*)(outh + 2097152);      // 64*8*32*16 ints (1MB)
  unsigned short* Wb = (unsigned short*)(flags + 64*8*32*16); // 768*256 bf16

  hipMemsetAsync(flags, 0, 64*8*32*16*sizeof(int), stream);
  k_uchar<<<CVOC, G3C, 0, stream>>>(cemb, cWih, cbih, cbhh, U2);
  k_w2bf<<<(G3C*CHc + 255)/256, 256, 0, stream>>>(cWhh, Wb, G3C*CHc);
  k_transpose<<<(G3H*KIN + 255)/256, 256, 0, stream>>>(gWih, WihTm, G3H, KIN);
  k_chargru<<<NTOK/16, 256, 0, stream>>>(chars, U2, Wb, cbhh, chh);
  k_gxmain<<<dim3(NTOK/128, G3H/96), 256, 0, stream>>>(x, wemb, chh, WihTm, gbih, gbhh, gx);
  k_grumain<<<256, 512, 0, stream>>>(gWhh, gx, gbhh, outh, flags);
  k_cls<<<TT, 256, 0, stream>>>(outh, clsW, clsb, out);
}